// Round 8
// baseline (349.555 us; speedup 1.0000x reference)
//
#include <hip/hip_runtime.h>
#include <math.h>

#define BATCH 8
#define NN    2048
#define FIN   512
#define FOUT  256
#define NEG_BIG -9000000000000000.0f

typedef __attribute__((ext_vector_type(8))) short bf16x8;   // 8 bf16 in 4 VGPR
typedef __attribute__((ext_vector_type(4))) float f32x4;    // MFMA accumulator

// round-to-nearest-even fp32 -> bf16 (inputs never NaN here)
__device__ __forceinline__ unsigned short f2bf(float x) {
    unsigned u = __float_as_uint(x);
    u = (u + 0x7FFF + ((u >> 16) & 1)) >> 16;
    return (unsigned short)u;
}
__device__ __forceinline__ float bf2f(unsigned short h) {
    return __uint_as_float(((unsigned)h) << 16);
}
// async global->LDS, 16B per lane: dest = (wave-uniform base) + lane*16
__device__ __forceinline__ void gload_lds16(const void* g, void* l) {
    __builtin_amdgcn_global_load_lds((const __attribute__((address_space(1))) void*)g,
                                     (__attribute__((address_space(3))) void*)l,
                                     16, 0, 0);
}

// ---------------------------------------------------------------------------
// Kernel 0: Wt_hi/Wt_lo[n][k] = split-bf16 of W[k][n]
// ---------------------------------------------------------------------------
__global__ __launch_bounds__(256) void wt_prep(const float* __restrict__ W,
                                               unsigned short* __restrict__ Wt_hi,
                                               unsigned short* __restrict__ Wt_lo) {
    const int tg = blockIdx.x * 256 + threadIdx.x;
    const int n  = tg >> 7;
    const int k4 = (tg & 127) * 4;
    unsigned short h[4], lo[4];
    #pragma unroll
    for (int i = 0; i < 4; i++) {
        const float v = W[(size_t)(k4 + i) * FOUT + n];
        h[i]  = f2bf(v);
        lo[i] = f2bf(v - bf2f(h[i]));
    }
    uint2 ph, pl;
    ph.x = h[0]  | ((unsigned)h[1]  << 16); ph.y = h[2]  | ((unsigned)h[3]  << 16);
    pl.x = lo[0] | ((unsigned)lo[1] << 16); pl.y = lo[2] | ((unsigned)lo[3] << 16);
    *(uint2*)(Wt_hi + (size_t)n * FIN + k4) = ph;
    *(uint2*)(Wt_lo + (size_t)n * FIN + k4) = pl;
}

// ---------------------------------------------------------------------------
// Kernel 1: ht = (x @ W)^T, split-bf16. (unchanged from r7 — passed, coalesced)
// ---------------------------------------------------------------------------
__global__ __launch_bounds__(256, 2) void gemm_xw(const float* __restrict__ x,
        const unsigned short* __restrict__ Wt_hi,
        const unsigned short* __restrict__ Wt_lo,
        unsigned short* __restrict__ ht_hi,
        unsigned short* __restrict__ ht_lo) {
    __shared__ unsigned short As_hi[128][40];
    __shared__ unsigned short As_lo[128][40];
    __shared__ __attribute__((aligned(16))) unsigned short Tr[64][136];
    const int t  = threadIdx.x;
    const int m0 = (blockIdx.x >> 2) * 128;
    const int n0 = (blockIdx.x & 3) * 64;
    const int l  = t & 63, w = t >> 6;
    const int wr = w >> 1, wc = w & 1;
    const int lr = l & 15, lk = l >> 4;

    f32x4 acc[4][2];
    #pragma unroll
    for (int mt = 0; mt < 4; mt++)
        #pragma unroll
        for (int nt = 0; nt < 2; nt++) acc[mt][nt] = (f32x4){0.f,0.f,0.f,0.f};

    for (int k0 = 0; k0 < FIN; k0 += 32) {
        float4 xv[4];
        #pragma unroll
        for (int r = 0; r < 4; r++) {
            const int fidx = t + 256*r, m = fidx >> 3, kq = fidx & 7;
            xv[r] = *(const float4*)(x + (size_t)(m0 + m) * FIN + k0 + kq*4);
        }
        bf16x8 bh[2], bl[2];
        #pragma unroll
        for (int nt = 0; nt < 2; nt++) {
            const size_t off = (size_t)(n0 + wc*32 + nt*16 + lr) * FIN + k0 + lk*8;
            bh[nt] = *(const bf16x8*)(Wt_hi + off);
            bl[nt] = *(const bf16x8*)(Wt_lo + off);
        }
        __syncthreads();
        #pragma unroll
        for (int r = 0; r < 4; r++) {
            const int fidx = t + 256*r, m = fidx >> 3, kq = fidx & 7;
            const float vv[4] = {xv[r].x, xv[r].y, xv[r].z, xv[r].w};
            unsigned short h[4], lo[4];
            #pragma unroll
            for (int i = 0; i < 4; i++) { h[i] = f2bf(vv[i]); lo[i] = f2bf(vv[i] - bf2f(h[i])); }
            uint2 ph, pl;
            ph.x = h[0]  | ((unsigned)h[1]  << 16); ph.y = h[2]  | ((unsigned)h[3]  << 16);
            pl.x = lo[0] | ((unsigned)lo[1] << 16); pl.y = lo[2] | ((unsigned)lo[3] << 16);
            *(uint2*)&As_hi[m][kq*4] = ph;
            *(uint2*)&As_lo[m][kq*4] = pl;
        }
        __syncthreads();
        bf16x8 ah[4], al[4];
        #pragma unroll
        for (int mt = 0; mt < 4; mt++) {
            const int row = wr*64 + mt*16 + lr;
            ah[mt] = *(const bf16x8*)&As_hi[row][lk*8];
            al[mt] = *(const bf16x8*)&As_lo[row][lk*8];
        }
        #pragma unroll
        for (int nt = 0; nt < 2; nt++)
            #pragma unroll
            for (int mt = 0; mt < 4; mt++)
                acc[mt][nt] = __builtin_amdgcn_mfma_f32_16x16x32_bf16(ah[mt], bh[nt], acc[mt][nt], 0, 0, 0);
        #pragma unroll
        for (int nt = 0; nt < 2; nt++)
            #pragma unroll
            for (int mt = 0; mt < 4; mt++)
                acc[mt][nt] = __builtin_amdgcn_mfma_f32_16x16x32_bf16(ah[mt], bl[nt], acc[mt][nt], 0, 0, 0);
        #pragma unroll
        for (int nt = 0; nt < 2; nt++)
            #pragma unroll
            for (int mt = 0; mt < 4; mt++)
                acc[mt][nt] = __builtin_amdgcn_mfma_f32_16x16x32_bf16(al[mt], bh[nt], acc[mt][nt], 0, 0, 0);
    }

    const int bb  = m0 >> 11;
    const int jj0 = m0 & 2047;
    for (int pass = 0; pass < 2; pass++) {
        #pragma unroll
        for (int mt = 0; mt < 4; mt++)
            #pragma unroll
            for (int nt = 0; nt < 2; nt++) {
                const int nl = wc*32 + nt*16 + lr;
                const int ml = wr*64 + mt*16 + lk*4;
                const float vv[4] = {acc[mt][nt].x, acc[mt][nt].y, acc[mt][nt].z, acc[mt][nt].w};
                unsigned short s[4];
                #pragma unroll
                for (int r = 0; r < 4; r++) {
                    const unsigned short hh = f2bf(vv[r]);
                    s[r] = pass ? f2bf(vv[r] - bf2f(hh)) : hh;
                }
                *(unsigned*)&Tr[nl][ml]     = s[0] | ((unsigned)s[1] << 16);
                *(unsigned*)&Tr[nl][ml + 2] = s[2] | ((unsigned)s[3] << 16);
            }
        __syncthreads();
        unsigned short* dst = pass ? ht_lo : ht_hi;
        #pragma unroll
        for (int q = 0; q < 4; q++) {
            const int idx = t + 256*q, row = idx >> 4, c = idx & 15;
            *(uint4*)(dst + ((size_t)(bb * FOUT + n0 + row)) * NN + jj0 + c*8) =
                *(const uint4*)&Tr[row][c*8];
        }
        __syncthreads();
    }
}

// ---------------------------------------------------------------------------
// Kernel 2: f = h@a1, g = h@a2. 256 blocks (was 64 -> 25% CU coverage),
// 4 waves split the n-loop, LDS reduce.
// ---------------------------------------------------------------------------
__global__ __launch_bounds__(256) void fg2(const unsigned short* __restrict__ ht_hi,
                                           const unsigned short* __restrict__ ht_lo,
                                           const float* __restrict__ a,
                                           float* __restrict__ f, float* __restrict__ g) {
    __shared__ float Fp[4][64], Gp[4][64];
    const int lane = threadIdx.x & 63, wv = threadIdx.x >> 6;
    const int chunk = blockIdx.x;            // 0..255
    const int b  = chunk >> 5;
    const int jw = (chunk & 31) * 64 + lane;
    const size_t base = (size_t)b * FOUT * NN + jw;
    float fs = 0.f, gs = 0.f;
    #pragma unroll 4
    for (int n = wv*64; n < wv*64 + 64; n++) {
        const float hv = bf2f(ht_hi[base + (size_t)n * NN]) + bf2f(ht_lo[base + (size_t)n * NN]);
        fs = fmaf(hv, a[n], fs);
        gs = fmaf(hv, a[FOUT + n], gs);
    }
    Fp[wv][lane] = fs; Gp[wv][lane] = gs;
    __syncthreads();
    if (wv == 0) {
        f[b * NN + jw] = Fp[0][lane] + Fp[1][lane] + Fp[2][lane] + Fp[3][lane];
        g[b * NN + jw] = Gp[0][lane] + Gp[1][lane] + Gp[2][lane] + Gp[3][lane];
    }
}

// ---------------------------------------------------------------------------
// Kernel 3: fused attention, ONE barrier per tile.
// 512 th = 8 waves (2x4: wr x wc), wave owns 32 i x 64 n. KVBLK=64.
// P computed IN-REGISTER per wave (4x redundant across wc): each lane's
// (row, j) slice of the rank-1 scores IS its MFMA A-fragment. m/l/fac in
// registers, exchanged to C-layout rows via intra-wave shfl. Hs double-
// buffered (128KB LDS): gload_lds issued right after the barrier, drained
// at the NEXT barrier (full-tile prefetch distance covers L2/L3 latency).
// ---------------------------------------------------------------------------
__global__ __launch_bounds__(512, 1) void gat_attn(
        const unsigned short* __restrict__ ht_hi,
        const unsigned short* __restrict__ ht_lo,
        const int* __restrict__ adj,
        const float* __restrict__ f, const float* __restrict__ g,
        float* __restrict__ out) {
    __shared__ __attribute__((aligned(16))) unsigned short Hs_hi[2][16384];
    __shared__ __attribute__((aligned(16))) unsigned short Hs_lo[2][16384];

    const int b  = blockIdx.x & 7;
    const int i0 = (blockIdx.x >> 3) * 64;
    const int t  = threadIdx.x;
    const int w  = t >> 6, l = t & 63;
    const int lr = l & 15, lk = l >> 4;
    const int wr = w >> 2, wc = w & 3;      // 2 i-halves x 4 n-quarters

    const unsigned short* hb_hi = ht_hi + (size_t)b * FOUT * NN;
    const unsigned short* hb_lo = ht_lo + (size_t)b * FOUT * NN;

    // per-lane A-rows: rowA[mt] = i0 + wr*32 + mt*16 + lr
    const int rbase = i0 + wr*32 + lr;
    const float fi0 = f[b*NN + rbase];
    const float fi1 = f[b*NN + rbase + 16];
    const int* adjr0 = adj + ((size_t)(b*NN + rbase)) * NN;
    const int* adjr1 = adjr0 + (size_t)16 * NN;
    const float* gb = g + b*NN;

    float m_reg[2] = {-INFINITY, -INFINITY};
    float l_reg[2] = {0.f, 0.f};
    f32x4 acc[2][4] = {};

    const int slot = w * 4;   // 4 staging chunks of 1KB per wave per array

    // adj/g prefetch registers (one tile ahead)
    int4   ap[2][2][2];       // [mt][kt][half]
    float4 gp[2][2];          // [kt][half]

    auto STAGE = [&](int jt, int buf) {
        const int j0 = jt * 64;
        #pragma unroll
        for (int q = 0; q < 4; q++) {
            const int idx = (slot + q) * 64 + l;
            const int n = idx >> 3, c = idx & 7;
            const int cc = c ^ (n & 7);                    // inverse swizzle on SOURCE
            const size_t go = (size_t)n * NN + j0 + cc * 8;
            gload_lds16(hb_hi + go, &Hs_hi[buf][(slot + q) * 512]);
            gload_lds16(hb_lo + go, &Hs_lo[buf][(slot + q) * 512]);
        }
    };
    auto LOADAG = [&](int jt) {
        const int j0 = jt * 64;
        #pragma unroll
        for (int kt = 0; kt < 2; kt++) {
            const int jo = j0 + kt*32 + lk*8;
            gp[kt][0]    = *(const float4*)(gb + jo);
            gp[kt][1]    = *(const float4*)(gb + jo + 4);
            ap[0][kt][0] = *(const int4*)(adjr0 + jo);
            ap[0][kt][1] = *(const int4*)(adjr0 + jo + 4);
            ap[1][kt][0] = *(const int4*)(adjr1 + jo);
            ap[1][kt][1] = *(const int4*)(adjr1 + jo + 4);
        }
    };

    STAGE(0, 0);
    LOADAG(0);

    for (int jt = 0; jt < 32; jt++) {
        const int buf = jt & 1;
        __syncthreads();                 // drains tile-jt staging; frees Hs[buf^1]
        if (jt + 1 < 32) STAGE(jt + 1, buf ^ 1);

        // ---- phase A (pure VALU + intra-wave shfl): P fragments in-register
        bf16x8 ph[2][2], pl[2][2];
        float fac[2];
        #pragma unroll
        for (int mt = 0; mt < 2; mt++) {
            const float fi = mt ? fi1 : fi0;
            float p[2][8];
            float mloc = -INFINITY;
            #pragma unroll
            for (int kt = 0; kt < 2; kt++) {
                const float gv[8] = {gp[kt][0].x, gp[kt][0].y, gp[kt][0].z, gp[kt][0].w,
                                     gp[kt][1].x, gp[kt][1].y, gp[kt][1].z, gp[kt][1].w};
                const int av[8] = {ap[mt][kt][0].x, ap[mt][kt][0].y, ap[mt][kt][0].z, ap[mt][kt][0].w,
                                   ap[mt][kt][1].x, ap[mt][kt][1].y, ap[mt][kt][1].z, ap[mt][kt][1].w};
                #pragma unroll
                for (int e = 0; e < 8; e++) {
                    const float v = fi + gv[e];
                    const float s = av[e] > 0 ? (v > 0.f ? v : 0.2f * v) : NEG_BIG;
                    p[kt][e] = s;                  // store score for now
                    mloc = fmaxf(mloc, s);
                }
            }
            mloc = fmaxf(mloc, __shfl_xor(mloc, 16));
            mloc = fmaxf(mloc, __shfl_xor(mloc, 32));
            const float mn = fmaxf(m_reg[mt], mloc);
            float rs = 0.f;
            #pragma unroll
            for (int kt = 0; kt < 2; kt++)
                #pragma unroll
                for (int e = 0; e < 8; e++) { p[kt][e] = __expf(p[kt][e] - mn); rs += p[kt][e]; }
            rs += __shfl_xor(rs, 16);
            rs += __shfl_xor(rs, 32);
            fac[mt]   = __expf(m_reg[mt] - mn);    // 0 on first tile
            l_reg[mt] = l_reg[mt] * fac[mt] + rs;
            m_reg[mt] = mn;
            #pragma unroll
            for (int kt = 0; kt < 2; kt++) {
                unsigned hw[4], lw[4];
                #pragma unroll
                for (int e = 0; e < 8; e += 2) {
                    const unsigned short h0 = f2bf(p[kt][e]),   h1 = f2bf(p[kt][e+1]);
                    const unsigned short q0 = f2bf(p[kt][e]   - bf2f(h0));
                    const unsigned short q1 = f2bf(p[kt][e+1] - bf2f(h1));
                    hw[e >> 1] = h0 | ((unsigned)h1 << 16);
                    lw[e >> 1] = q0 | ((unsigned)q1 << 16);
                }
                ph[mt][kt] = (bf16x8)__builtin_bit_cast(bf16x8, make_uint4(hw[0], hw[1], hw[2], hw[3]));
                pl[mt][kt] = (bf16x8)__builtin_bit_cast(bf16x8, make_uint4(lw[0], lw[1], lw[2], lw[3]));
            }
        }

        if (jt + 1 < 32) LOADAG(jt + 1);   // lands during MFMA, drained next barrier

        // ---- rescale acc: fac gathered to C-layout rows via shfl ----
        #pragma unroll
        for (int mt = 0; mt < 2; mt++) {
            f32x4 f4;
            #pragma unroll
            for (int r = 0; r < 4; r++) f4[r] = __shfl(fac[mt], lk*4 + r);
            #pragma unroll
            for (int nt = 0; nt < 4; nt++) acc[mt][nt] *= f4;
        }

        // ---- MFMA PV (3-product split), B-frags from swizzled Hs[buf] ----
        #pragma unroll
        for (int kt = 0; kt < 2; kt++) {
            bf16x8 bh[4], bl[4];
            #pragma unroll
            for (int nt = 0; nt < 4; nt++) {
                const int n  = wc*64 + nt*16 + lr;
                const int cs = ((kt*4 + lk) ^ (n & 7)) * 8;
                bh[nt] = *(const bf16x8*)&Hs_hi[buf][n * 64 + cs];
                bl[nt] = *(const bf16x8*)&Hs_lo[buf][n * 64 + cs];
            }
            #pragma unroll
            for (int nt = 0; nt < 4; nt++)
                #pragma unroll
                for (int mt = 0; mt < 2; mt++)
                    acc[mt][nt] = __builtin_amdgcn_mfma_f32_16x16x32_bf16(ph[mt][kt], bh[nt], acc[mt][nt], 0, 0, 0);
            #pragma unroll
            for (int nt = 0; nt < 4; nt++)
                #pragma unroll
                for (int mt = 0; mt < 2; mt++)
                    acc[mt][nt] = __builtin_amdgcn_mfma_f32_16x16x32_bf16(ph[mt][kt], bl[nt], acc[mt][nt], 0, 0, 0);
            #pragma unroll
            for (int nt = 0; nt < 4; nt++)
                #pragma unroll
                for (int mt = 0; mt < 2; mt++)
                    acc[mt][nt] = __builtin_amdgcn_mfma_f32_16x16x32_bf16(pl[mt][kt], bh[nt], acc[mt][nt], 0, 0, 0);
        }
    }

    // ---- epilogue: l gathered to C-layout rows via shfl; ELU; store ----
    #pragma unroll
    for (int mt = 0; mt < 2; mt++) {
        float li[4];
        #pragma unroll
        for (int r = 0; r < 4; r++) li[r] = 1.f / __shfl(l_reg[mt], lk*4 + r);
        #pragma unroll
        for (int nt = 0; nt < 4; nt++) {
            const int n = wc*64 + nt*16 + lr;
            const float av[4] = {acc[mt][nt].x, acc[mt][nt].y, acc[mt][nt].z, acc[mt][nt].w};
            #pragma unroll
            for (int r = 0; r < 4; r++) {
                float v = av[r] * li[r];
                v = v > 0.f ? v : (__expf(v) - 1.f);
                out[((size_t)(b * NN + i0 + wr*32 + mt*16 + lk*4 + r)) * FOUT + n] = v;
            }
        }
    }
}

// ---------------------------------------------------------------------------
extern "C" void kernel_launch(void* const* d_in, const int* in_sizes, int n_in,
                              void* d_out, int out_size, void* d_ws, size_t ws_size,
                              hipStream_t stream) {
    const float* x   = (const float*)d_in[0];   // (8, 2048, 512)
    const int*   adj = (const int*)  d_in[1];   // (8, 2048, 2048)
    const float* W   = (const float*)d_in[2];   // (512, 256)
    const float* a   = (const float*)d_in[3];   // (512, 1)
    float* outp = (float*)d_out;                // (8, 2048, 256) fp32

    char* ws = (char*)d_ws;
    unsigned short* ht_hi = (unsigned short*)ws;                       ws += (size_t)BATCH*FOUT*NN*2;
    unsigned short* ht_lo = (unsigned short*)ws;                       ws += (size_t)BATCH*FOUT*NN*2;
    unsigned short* Wt_hi = (unsigned short*)ws;                       ws += (size_t)FOUT*FIN*2;
    unsigned short* Wt_lo = (unsigned short*)ws;                       ws += (size_t)FOUT*FIN*2;
    float* f = (float*)ws;                                             ws += (size_t)BATCH*NN*4;
    float* g = (float*)ws;

    wt_prep <<<128, 256, 0, stream>>>(W, Wt_hi, Wt_lo);
    gemm_xw <<<512, 256, 0, stream>>>(x, Wt_hi, Wt_lo, ht_hi, ht_lo);
    fg2     <<<256, 256, 0, stream>>>(ht_hi, ht_lo, a, f, g);
    gat_attn<<<256, 512, 0, stream>>>(ht_hi, ht_lo, adj, f, g, outp);
}

// Round 9
// 287.329 us; speedup vs baseline: 1.2166x; 1.2166x over previous
//
#include <hip/hip_runtime.h>
#include <hip/hip_bf16.h>
#include <math.h>

#define BATCH 8
#define NN    2048
#define FIN   512
#define FOUT  256
#define NEG_BIG -9000000000000000.0f

typedef __attribute__((ext_vector_type(8))) short bf16x8;   // 8 bf16 in 4 VGPR
typedef __attribute__((ext_vector_type(4))) float f32x4;    // MFMA accumulator

// HW RNE fp32->bf16 (pairs fuse to v_cvt_pk_bf16_f32); inputs never NaN.
__device__ __forceinline__ unsigned short f2bf(float x) {
    return __bfloat16_as_ushort(__float2bfloat16(x));
}
__device__ __forceinline__ float bf2f(unsigned short h) {
    return __uint_as_float(((unsigned)h) << 16);
}
// async global->LDS, 16B per lane: dest = (wave-uniform base) + lane*16
__device__ __forceinline__ void gload_lds16(const void* g, void* l) {
    __builtin_amdgcn_global_load_lds((const __attribute__((address_space(1))) void*)g,
                                     (__attribute__((address_space(3))) void*)l,
                                     16, 0, 0);
}
// raw barrier: orders LDS (lgkmcnt only) — does NOT drain vmcnt, so
// global_load_lds staging issued before it stays in flight across the barrier.
__device__ __forceinline__ void lds_barrier() {
    asm volatile("s_waitcnt lgkmcnt(0)" ::: "memory");
    __builtin_amdgcn_s_barrier();
    asm volatile("" ::: "memory");          // compile-time fence: no mem op crosses
}

// ---------------------------------------------------------------------------
// Kernel 0: Wtf_hi/lo = split-bf16 of W in MFMA FRAGMENT order:
// addr = ((ktile*16 + ntile)*64 + lane)*8 + e, lane = ((k>>3)&3)*16 + (n&15),
// ktile=k>>5, ntile=n>>4, e=k&7. B-frag loads in gemm become contiguous 1KB
// wave streams (old layout: 16-cacheline gather per load).
// ---------------------------------------------------------------------------
__global__ __launch_bounds__(256) void wt_prep(const float* __restrict__ W,
                                               unsigned short* __restrict__ Wtf_hi,
                                               unsigned short* __restrict__ Wtf_lo) {
    const int tg = blockIdx.x * 256 + threadIdx.x;   // 32768 threads
    const int n  = tg >> 7;                          // 0..255
    const int k4 = (tg & 127) * 4;                   // 0..508, step 4
    unsigned short h[4], lo[4];
    #pragma unroll
    for (int i = 0; i < 4; i++) {
        const float v = W[(size_t)(k4 + i) * FOUT + n];
        h[i]  = f2bf(v);
        lo[i] = f2bf(v - bf2f(h[i]));
    }
    const int ktile = k4 >> 5;
    const int ntile = n >> 4;
    const int lane  = ((k4 >> 3) & 3) * 16 + (n & 15);
    const size_t daddr = ((size_t)(ktile * 16 + ntile) * 64 + lane) * 8 + (k4 & 7);
    uint2 ph, pl;
    ph.x = h[0]  | ((unsigned)h[1]  << 16); ph.y = h[2]  | ((unsigned)h[3]  << 16);
    pl.x = lo[0] | ((unsigned)lo[1] << 16); pl.y = lo[2] | ((unsigned)lo[3] << 16);
    *(uint2*)(Wtf_hi + daddr) = ph;
    *(uint2*)(Wtf_lo + daddr) = pl;
}

// ---------------------------------------------------------------------------
// Kernel 1: ht = (x @ W)^T, split-bf16. B-frags from fragment-ordered Wtf
// (coalesced). LDS-transpose epilogue -> coalesced 256B-row stores.
// ---------------------------------------------------------------------------
__global__ __launch_bounds__(256, 2) void gemm_xw(const float* __restrict__ x,
        const unsigned short* __restrict__ Wtf_hi,
        const unsigned short* __restrict__ Wtf_lo,
        unsigned short* __restrict__ ht_hi,
        unsigned short* __restrict__ ht_lo) {
    __shared__ unsigned short As_hi[128][40];
    __shared__ unsigned short As_lo[128][40];
    __shared__ __attribute__((aligned(16))) unsigned short Tr[64][136];
    const int t  = threadIdx.x;
    const int m0 = (blockIdx.x >> 2) * 128;
    const int n0 = (blockIdx.x & 3) * 64;
    const int l  = t & 63, w = t >> 6;
    const int wr = w >> 1, wc = w & 1;
    const int lr = l & 15, lk = l >> 4;

    f32x4 acc[4][2];
    #pragma unroll
    for (int mt = 0; mt < 4; mt++)
        #pragma unroll
        for (int nt = 0; nt < 2; nt++) acc[mt][nt] = (f32x4){0.f,0.f,0.f,0.f};

    for (int k0 = 0; k0 < FIN; k0 += 32) {
        float4 xv[4];
        #pragma unroll
        for (int r = 0; r < 4; r++) {
            const int fidx = t + 256*r, m = fidx >> 3, kq = fidx & 7;
            xv[r] = *(const float4*)(x + (size_t)(m0 + m) * FIN + k0 + kq*4);
        }
        // B frags: fragment-ordered, per-wave contiguous 1KB loads
        bf16x8 bh[2], bl[2];
        const size_t fb = ((size_t)((k0 >> 5) * 16 + (n0 >> 4) + wc*2) * 64 + l) * 8;
        #pragma unroll
        for (int nt = 0; nt < 2; nt++) {
            bh[nt] = *(const bf16x8*)(Wtf_hi + fb + (size_t)nt * 512);
            bl[nt] = *(const bf16x8*)(Wtf_lo + fb + (size_t)nt * 512);
        }
        __syncthreads();
        #pragma unroll
        for (int r = 0; r < 4; r++) {
            const int fidx = t + 256*r, m = fidx >> 3, kq = fidx & 7;
            const float vv[4] = {xv[r].x, xv[r].y, xv[r].z, xv[r].w};
            unsigned short h[4], lo[4];
            #pragma unroll
            for (int i = 0; i < 4; i++) { h[i] = f2bf(vv[i]); lo[i] = f2bf(vv[i] - bf2f(h[i])); }
            uint2 ph, pl;
            ph.x = h[0]  | ((unsigned)h[1]  << 16); ph.y = h[2]  | ((unsigned)h[3]  << 16);
            pl.x = lo[0] | ((unsigned)lo[1] << 16); pl.y = lo[2] | ((unsigned)lo[3] << 16);
            *(uint2*)&As_hi[m][kq*4] = ph;
            *(uint2*)&As_lo[m][kq*4] = pl;
        }
        __syncthreads();
        bf16x8 ah[4], al[4];
        #pragma unroll
        for (int mt = 0; mt < 4; mt++) {
            const int row = wr*64 + mt*16 + lr;
            ah[mt] = *(const bf16x8*)&As_hi[row][lk*8];
            al[mt] = *(const bf16x8*)&As_lo[row][lk*8];
        }
        #pragma unroll
        for (int nt = 0; nt < 2; nt++)
            #pragma unroll
            for (int mt = 0; mt < 4; mt++)
                acc[mt][nt] = __builtin_amdgcn_mfma_f32_16x16x32_bf16(ah[mt], bh[nt], acc[mt][nt], 0, 0, 0);
        #pragma unroll
        for (int nt = 0; nt < 2; nt++)
            #pragma unroll
            for (int mt = 0; mt < 4; mt++)
                acc[mt][nt] = __builtin_amdgcn_mfma_f32_16x16x32_bf16(ah[mt], bl[nt], acc[mt][nt], 0, 0, 0);
        #pragma unroll
        for (int nt = 0; nt < 2; nt++)
            #pragma unroll
            for (int mt = 0; mt < 4; mt++)
                acc[mt][nt] = __builtin_amdgcn_mfma_f32_16x16x32_bf16(al[mt], bh[nt], acc[mt][nt], 0, 0, 0);
    }

    const int bb  = m0 >> 11;
    const int jj0 = m0 & 2047;
    for (int pass = 0; pass < 2; pass++) {
        #pragma unroll
        for (int mt = 0; mt < 4; mt++)
            #pragma unroll
            for (int nt = 0; nt < 2; nt++) {
                const int nl = wc*32 + nt*16 + lr;
                const int ml = wr*64 + mt*16 + lk*4;
                const float vv[4] = {acc[mt][nt].x, acc[mt][nt].y, acc[mt][nt].z, acc[mt][nt].w};
                unsigned short s[4];
                #pragma unroll
                for (int r = 0; r < 4; r++) {
                    const unsigned short hh = f2bf(vv[r]);
                    s[r] = pass ? f2bf(vv[r] - bf2f(hh)) : hh;
                }
                *(unsigned*)&Tr[nl][ml]     = s[0] | ((unsigned)s[1] << 16);
                *(unsigned*)&Tr[nl][ml + 2] = s[2] | ((unsigned)s[3] << 16);
            }
        __syncthreads();
        unsigned short* dst = pass ? ht_lo : ht_hi;
        #pragma unroll
        for (int q = 0; q < 4; q++) {
            const int idx = t + 256*q, row = idx >> 4, c = idx & 15;
            *(uint4*)(dst + ((size_t)(bb * FOUT + n0 + row)) * NN + jj0 + c*8) =
                *(const uint4*)&Tr[row][c*8];
        }
        __syncthreads();
    }
}

// ---------------------------------------------------------------------------
// Kernel 2: f = h@a1, g = h@a2. 256 blocks, 4 waves split the n-loop, LDS reduce.
// ---------------------------------------------------------------------------
__global__ __launch_bounds__(256) void fg2(const unsigned short* __restrict__ ht_hi,
                                           const unsigned short* __restrict__ ht_lo,
                                           const float* __restrict__ a,
                                           float* __restrict__ f, float* __restrict__ g) {
    __shared__ float Fp[4][64], Gp[4][64];
    const int lane = threadIdx.x & 63, wv = threadIdx.x >> 6;
    const int chunk = blockIdx.x;            // 0..255
    const int b  = chunk >> 5;
    const int jw = (chunk & 31) * 64 + lane;
    const size_t base = (size_t)b * FOUT * NN + jw;
    float fs = 0.f, gs = 0.f;
    #pragma unroll 4
    for (int n = wv*64; n < wv*64 + 64; n++) {
        const float hv = bf2f(ht_hi[base + (size_t)n * NN]) + bf2f(ht_lo[base + (size_t)n * NN]);
        fs = fmaf(hv, a[n], fs);
        gs = fmaf(hv, a[FOUT + n], gs);
    }
    Fp[wv][lane] = fs; Gp[wv][lane] = gs;
    __syncthreads();
    if (wv == 0) {
        f[b * NN + jw] = Fp[0][lane] + Fp[1][lane] + Fp[2][lane] + Fp[3][lane];
        g[b * NN + jw] = Gp[0][lane] + Gp[1][lane] + Gp[2][lane] + Gp[3][lane];
    }
}

// ---------------------------------------------------------------------------
// Kernel 3: fused attention. 512 th = 8 waves (2wr x 4wc), wave = 32i x 64n.
// SHARED P (no redundancy): phase A thread = (row ar=t>>3, j-octet jg=t&7),
// softmax state in registers (8-lane groups, shfl), P split-bf16 -> LDS
// (XOR-swizzled). Raw lds_barrier (no vmcnt drain): Hs double-buffer staging
// spans a full tile; adj/g reg-prefetch issued AFTER STAGE (fence-pinned) so
// the compiler's automatic vmcnt wait for those regs also drains STAGE(t).
// ---------------------------------------------------------------------------
__global__ __launch_bounds__(512, 1) void gat_attn(
        const unsigned short* __restrict__ ht_hi,
        const unsigned short* __restrict__ ht_lo,
        const int* __restrict__ adj,
        const float* __restrict__ f, const float* __restrict__ g,
        float* __restrict__ out) {
    __shared__ __attribute__((aligned(16))) unsigned short Hs_hi[2][16384];
    __shared__ __attribute__((aligned(16))) unsigned short Hs_lo[2][16384];
    __shared__ __attribute__((aligned(16))) unsigned short Ps_hi[4096];
    __shared__ __attribute__((aligned(16))) unsigned short Ps_lo[4096];
    __shared__ __attribute__((aligned(16))) float fac_s[64];
    __shared__ __attribute__((aligned(16))) float l_s[64];

    const int b  = blockIdx.x & 7;
    const int i0 = (blockIdx.x >> 3) * 64;
    const int t  = threadIdx.x;
    const int w  = t >> 6, l = t & 63;
    const int lr = l & 15, lk = l >> 4;
    const int wr = w >> 2, wc = w & 3;      // 2 i-halves x 4 n-quarters
    const int ar = t >> 3, jg = t & 7;      // phase A: row 0..63, j-octet 0..7

    const unsigned short* hb_hi = ht_hi + (size_t)b * FOUT * NN;
    const unsigned short* hb_lo = ht_lo + (size_t)b * FOUT * NN;
    const int*   adjr = adj + ((size_t)(b * NN + i0 + ar)) * NN + jg * 8;
    const float* gb   = g + b * NN + jg * 8;
    const float  fi   = f[b * NN + i0 + ar];

    float m_r = -INFINITY, l_r = 0.f;       // replicated across the 8-lane group
    f32x4 acc[2][4] = {};
    const int slot = w * 4;                 // 4 staging chunks/wave/array

    int4 a0v, a1v; float4 g0v, g1v;         // adj/g prefetch (1 tile ahead)

    auto STAGE = [&](int jt) {
        const int buf = jt & 1, j0 = jt * 64;
        #pragma unroll
        for (int q = 0; q < 4; q++) {
            const int idx = (slot + q) * 64 + l;
            const int n = idx >> 3, c = idx & 7;
            const int cc = c ^ (n & 7);                    // inverse swizzle on SOURCE
            const size_t go = (size_t)n * NN + j0 + cc * 8;
            gload_lds16(hb_hi + go, &Hs_hi[buf][(slot + q) * 512]);
            gload_lds16(hb_lo + go, &Hs_lo[buf][(slot + q) * 512]);
        }
    };
    auto LOADAG = [&](int jt) {
        const size_t jo = (size_t)jt * 64;
        a0v = *(const int4*)(adjr + jo);
        a1v = *(const int4*)(adjr + jo + 4);
        g0v = *(const float4*)(gb + jo);
        g1v = *(const float4*)(gb + jo + 4);
    };

    STAGE(0);
    asm volatile("" ::: "memory");          // pin: STAGE(t) issues before LOADAG(t)
    LOADAG(0);

    for (int jt = 0; jt < 32; jt++) {
        const int buf = jt & 1;
        if (jt + 1 < 32) STAGE(jt + 1);     // writes Hs[buf^1]; in flight across B1
        asm volatile("" ::: "memory");

        // ---- phase A: scores + online softmax (regs) + P split-bf16 -> LDS ----
        {
            float p[8];
            {
                const float v0 = fi + g0v.x, v1 = fi + g0v.y, v2 = fi + g0v.z, v3 = fi + g0v.w;
                const float v4 = fi + g1v.x, v5 = fi + g1v.y, v6 = fi + g1v.z, v7 = fi + g1v.w;
                p[0] = a0v.x > 0 ? (v0 > 0.f ? v0 : 0.2f*v0) : NEG_BIG;
                p[1] = a0v.y > 0 ? (v1 > 0.f ? v1 : 0.2f*v1) : NEG_BIG;
                p[2] = a0v.z > 0 ? (v2 > 0.f ? v2 : 0.2f*v2) : NEG_BIG;
                p[3] = a0v.w > 0 ? (v3 > 0.f ? v3 : 0.2f*v3) : NEG_BIG;
                p[4] = a1v.x > 0 ? (v4 > 0.f ? v4 : 0.2f*v4) : NEG_BIG;
                p[5] = a1v.y > 0 ? (v5 > 0.f ? v5 : 0.2f*v5) : NEG_BIG;
                p[6] = a1v.z > 0 ? (v6 > 0.f ? v6 : 0.2f*v6) : NEG_BIG;
                p[7] = a1v.w > 0 ? (v7 > 0.f ? v7 : 0.2f*v7) : NEG_BIG;
            }
            float mloc = p[0];
            #pragma unroll
            for (int e = 1; e < 8; e++) mloc = fmaxf(mloc, p[e]);
            mloc = fmaxf(mloc, __shfl_xor(mloc, 1));
            mloc = fmaxf(mloc, __shfl_xor(mloc, 2));
            mloc = fmaxf(mloc, __shfl_xor(mloc, 4));
            const float mn = fmaxf(m_r, mloc);
            float rs = 0.f;
            #pragma unroll
            for (int e = 0; e < 8; e++) { p[e] = __expf(p[e] - mn); rs += p[e]; }
            rs += __shfl_xor(rs, 1);
            rs += __shfl_xor(rs, 2);
            rs += __shfl_xor(rs, 4);
            const float fac = __expf(m_r - mn);     // 0 on first tile
            l_r = l_r * fac + rs;
            m_r = mn;
            if (jg == 0) { fac_s[ar] = fac; l_s[ar] = l_r; }
            unsigned hw_[4], lw_[4];
            #pragma unroll
            for (int e = 0; e < 8; e += 2) {
                const unsigned short h0 = f2bf(p[e]),   h1 = f2bf(p[e+1]);
                const unsigned short q0 = f2bf(p[e]   - bf2f(h0));
                const unsigned short q1 = f2bf(p[e+1] - bf2f(h1));
                hw_[e >> 1] = h0 | ((unsigned)h1 << 16);
                lw_[e >> 1] = q0 | ((unsigned)q1 << 16);
            }
            const int cs = (jg ^ (ar & 7)) * 8;
            *(uint4*)&Ps_hi[ar * 64 + cs] = make_uint4(hw_[0], hw_[1], hw_[2], hw_[3]);
            *(uint4*)&Ps_lo[ar * 64 + cs] = make_uint4(lw_[0], lw_[1], lw_[2], lw_[3]);
        }

        if (jt + 1 < 32) LOADAG(jt + 1);    // after STAGE in FIFO; lands during MFMA

        lds_barrier();                      // B1: Ps/fac visible; Hs[buf] staged
                                            // (phase A's reg wait drained STAGE(t))

        // ---- phase B: rescale + MFMA PV (3-product split) ----
        #pragma unroll
        for (int mt = 0; mt < 2; mt++) {
            const f32x4 fac4 = *(const f32x4*)&fac_s[wr*32 + mt*16 + lk*4];  // broadcast
            #pragma unroll
            for (int nt = 0; nt < 4; nt++) acc[mt][nt] *= fac4;
        }
        __builtin_amdgcn_s_setprio(1);
        #pragma unroll
        for (int kt = 0; kt < 2; kt++) {
            bf16x8 ah[2], al[2], bh[4], bl[4];
            #pragma unroll
            for (int mt = 0; mt < 2; mt++) {
                const int row = wr*32 + mt*16 + lr;
                const int cs  = ((kt*4 + lk) ^ (row & 7)) * 8;
                ah[mt] = *(const bf16x8*)&Ps_hi[row * 64 + cs];
                al[mt] = *(const bf16x8*)&Ps_lo[row * 64 + cs];
            }
            #pragma unroll
            for (int nt = 0; nt < 4; nt++) {
                const int n  = wc*64 + nt*16 + lr;
                const int cs = ((kt*4 + lk) ^ (n & 7)) * 8;
                bh[nt] = *(const bf16x8*)&Hs_hi[buf][n * 64 + cs];
                bl[nt] = *(const bf16x8*)&Hs_lo[buf][n * 64 + cs];
            }
            #pragma unroll
            for (int nt = 0; nt < 4; nt++)
                #pragma unroll
                for (int mt = 0; mt < 2; mt++)
                    acc[mt][nt] = __builtin_amdgcn_mfma_f32_16x16x32_bf16(ah[mt], bh[nt], acc[mt][nt], 0, 0, 0);
            #pragma unroll
            for (int nt = 0; nt < 4; nt++)
                #pragma unroll
                for (int mt = 0; mt < 2; mt++)
                    acc[mt][nt] = __builtin_amdgcn_mfma_f32_16x16x32_bf16(ah[mt], bl[nt], acc[mt][nt], 0, 0, 0);
            #pragma unroll
            for (int nt = 0; nt < 4; nt++)
                #pragma unroll
                for (int mt = 0; mt < 2; mt++)
                    acc[mt][nt] = __builtin_amdgcn_mfma_f32_16x16x32_bf16(al[mt], bh[nt], acc[mt][nt], 0, 0, 0);
        }
        __builtin_amdgcn_s_setprio(0);

        lds_barrier();                      // B2: reads of Ps/Hs[buf] done before
                                            // next phase A / STAGE overwrite them
    }

    // ---- epilogue: 1/l via LDS (written by owner in last phase A); ELU; store
    #pragma unroll
    for (int mt = 0; mt < 2; mt++) {
        const f32x4 lv = *(const f32x4*)&l_s[wr*32 + mt*16 + lk*4];
        const float li[4] = {1.f/lv.x, 1.f/lv.y, 1.f/lv.z, 1.f/lv.w};
        #pragma unroll
        for (int nt = 0; nt < 4; nt++) {
            const int n = wc*64 + nt*16 + lr;
            const float av[4] = {acc[mt][nt].x, acc[mt][nt].y, acc[mt][nt].z, acc[mt][nt].w};
            #pragma unroll
            for (int r = 0; r < 4; r++) {
                float v = av[r] * li[r];
                v = v > 0.f ? v : (__expf(v) - 1.f);
                out[((size_t)(b * NN + i0 + wr*32 + mt*16 + lk*4 + r)) * FOUT + n] = v;
            }
        }
    }
}

// ---------------------------------------------------------------------------
extern "C" void kernel_launch(void* const* d_in, const int* in_sizes, int n_in,
                              void* d_out, int out_size, void* d_ws, size_t ws_size,
                              hipStream_t stream) {
    const float* x   = (const float*)d_in[0];   // (8, 2048, 512)
    const int*   adj = (const int*)  d_in[1];   // (8, 2048, 2048)
    const float* W   = (const float*)d_in[2];   // (512, 256)
    const float* a   = (const float*)d_in[3];   // (512, 1)
    float* outp = (float*)d_out;                // (8, 2048, 256) fp32

    char* ws = (char*)d_ws;
    unsigned short* ht_hi  = (unsigned short*)ws;                      ws += (size_t)BATCH*FOUT*NN*2;
    unsigned short* ht_lo  = (unsigned short*)ws;                      ws += (size_t)BATCH*FOUT*NN*2;
    unsigned short* Wtf_hi = (unsigned short*)ws;                      ws += (size_t)FOUT*FIN*2;
    unsigned short* Wtf_lo = (unsigned short*)ws;                      ws += (size_t)FOUT*FIN*2;
    float* f = (float*)ws;                                             ws += (size_t)BATCH*NN*4;
    float* g = (float*)ws;

    wt_prep <<<128, 256, 0, stream>>>(W, Wtf_hi, Wtf_lo);
    gemm_xw <<<512, 256, 0, stream>>>(x, Wtf_hi, Wtf_lo, ht_hi, ht_lo);
    fg2     <<<256, 256, 0, stream>>>(ht_hi, ht_lo, a, f, g);
    gat_attn<<<256, 512, 0, stream>>>(ht_hi, ht_lo, adj, f, g, outp);
}